// Round 3
// baseline (596.127 us; speedup 1.0000x reference)
//
#include <hip/hip_runtime.h>
#include <hip/hip_bf16.h>
#include <stdint.h>

#define B_ 8
#define N_ 8192
#define DIM_ 512
#define H_ 8
#define DH_ 64
#define ROWS (B_*N_)        // 65536
#define TRIPLE (3*DIM_)     // 1536
#define EPS_ 1e-5f

typedef __attribute__((ext_vector_type(8))) short short8;
typedef __attribute__((ext_vector_type(4))) float f32x4;
typedef __attribute__((ext_vector_type(4))) float fl4;
typedef __attribute__((ext_vector_type(4))) unsigned short us4;

#define AS1 __attribute__((address_space(1)))
#define AS3 __attribute__((address_space(3)))

__device__ __forceinline__ void gld16(const void* g, void* l) {
    __builtin_amdgcn_global_load_lds((const AS1 void*)(uintptr_t)g,
                                     (AS3 void*)(unsigned)(uintptr_t)l, 16, 0, 0);
}

__device__ inline unsigned short f2bf(float f) {
    union { float f; unsigned int u; } x; x.f = f;
    unsigned int r = x.u + 0x7fffu + ((x.u >> 16) & 1u);
    return (unsigned short)(r >> 16);
}
__device__ inline float bf2f(unsigned short b) {
    union { unsigned int u; float f; } x; x.u = ((unsigned int)b) << 16;
    return x.f;
}

// ---------------------------------------------------------------------------
// k_prep: wqkvT[n][k] = bf16(w_qkv[k][n]);  wo2T[n][k] = bf16(lnw[k]*w_out[k][n])
__global__ void k_prep(const float* __restrict__ w_qkv, const float* __restrict__ w_out,
                       const float* __restrict__ lnw,
                       unsigned short* __restrict__ wqkvT, unsigned short* __restrict__ wo2T) {
    int idx = blockIdx.x * 256 + threadIdx.x;
    if (idx < TRIPLE * DIM_) {
        int n = idx / DIM_, k = idx - n * DIM_;
        wqkvT[idx] = f2bf(w_qkv[(size_t)k * TRIPLE + n]);
    }
    if (idx < DIM_ * DIM_) {
        int n = idx >> 9, k = idx & 511;
        wo2T[idx] = f2bf(lnw[k] * w_out[(size_t)k * DIM_ + n]);
    }
}

// k_sums: s[n] = sum_k lnw[k]*w_out[k][n];  tb[n] = sum_k lnb[k]*w_out[k][n] + b_out[n]
__global__ void k_sums(const float* __restrict__ w_out, const float* __restrict__ lnw,
                       const float* __restrict__ lnb, const float* __restrict__ bout,
                       float* __restrict__ s, float* __restrict__ tb) {
    int n = blockIdx.x * 256 + threadIdx.x;
    if (n >= 512) return;
    float ss = 0.f, tt = 0.f;
#pragma unroll 8
    for (int k = 0; k < 512; ++k) {
        float w = w_out[(size_t)k * 512 + n];
        ss += lnw[k] * w;
        tt += lnb[k] * w;
    }
    s[n] = ss;
    tb[n] = tt + bout[n];
}

// ---------------------------------------------------------------------------
// k_qkv_b: C = x(fp32) @ w_qkv, fp32 A staged via global_load_lds with
// XOR-swizzled 16B granules (coalesced loads AND conflict-free ds_read_b128),
// packed cvt to bf16 in the frag path.  relu on cols<1024.  No k_cvt pass.
__global__ __launch_bounds__(256) void k_qkv_b(const float* __restrict__ x,
        const unsigned short* __restrict__ wT,      // [1536][512] bf16
        unsigned short* __restrict__ qkv)           // [65536][1536] bf16
{
    __shared__ float As[128 * 32];                  // swizzled granules, 16 KB
    __shared__ unsigned short Bs[128 * 32];         // row-major, 8 KB
    int t = threadIdx.x;
    int lane = t & 63, wave = t >> 6;
    int m0 = blockIdx.y * 128;
    int n0 = blockIdx.x * 128;
    int wm = (wave & 1) * 64, wn = (wave >> 1) * 64;
    int lr = lane & 15, kg = (lane >> 4) * 8;
    int kc0 = (lane >> 4) * 2;                      // fp32 granule index of frag

    f32x4 acc[4][4] = {};
    for (int k0 = 0; k0 < DIM_; k0 += 32) {
        // A: 16 calls; granule g: row=g>>3, stored slot (g&7), holds global
        // granule ((g&7) ^ (row&7))  -> coalesced 128B rows, swizzled in LDS
#pragma unroll
        for (int i = 0; i < 4; ++i) {
            int c = wave * 4 + i;                   // 0..15
            int g = c * 64 + lane;
            int r = g >> 3, kc = g & 7;
            gld16(x + (size_t)(m0 + r) * DIM_ + k0 + ((kc ^ (r & 7)) << 2),
                  (char*)As + c * 1024);
        }
        // B: 8 calls, row-major [128][32] bf16
#pragma unroll
        for (int i = 0; i < 2; ++i) {
            int c = wave * 2 + i;                   // 0..7
            int r = c * 16 + (lane >> 2);
            gld16(wT + (size_t)(n0 + r) * DIM_ + k0 + (lane & 3) * 8,
                  (char*)Bs + c * 1024);
        }
        __syncthreads();
        short8 af[4], bfr[4];
#pragma unroll
        for (int i = 0; i < 4; ++i) {
            int m = wm + i * 16 + lr;
            f32x4 a0 = *(f32x4*)&As[(m * 8 + (kc0 ^ (m & 7))) * 4];
            f32x4 a1 = *(f32x4*)&As[(m * 8 + ((kc0 + 1) ^ (m & 7))) * 4];
            union { short8 s8; __hip_bfloat162 h2[4]; } u;
            u.h2[0] = __float22bfloat162_rn(float2{a0[0], a0[1]});
            u.h2[1] = __float22bfloat162_rn(float2{a0[2], a0[3]});
            u.h2[2] = __float22bfloat162_rn(float2{a1[0], a1[1]});
            u.h2[3] = __float22bfloat162_rn(float2{a1[2], a1[3]});
            af[i] = u.s8;
        }
#pragma unroll
        for (int j = 0; j < 4; ++j) bfr[j] = *(short8*)&Bs[(wn + j * 16 + lr) * 32 + kg];
#pragma unroll
        for (int i = 0; i < 4; ++i)
#pragma unroll
            for (int j = 0; j < 4; ++j)
                acc[i][j] = __builtin_amdgcn_mfma_f32_16x16x32_bf16(af[i], bfr[j], acc[i][j], 0, 0, 0);
        __syncthreads();
    }
#pragma unroll
    for (int i = 0; i < 4; ++i) {
        int row = m0 + wm + i * 16 + (lane >> 4) * 4;
#pragma unroll
        for (int j = 0; j < 4; ++j) {
            int col = n0 + wn + j * 16 + lr;
            bool rl = (col < 1024);
#pragma unroll
            for (int r = 0; r < 4; ++r) {
                float v = acc[i][j][r];
                if (rl && v < 0.0f) v = 0.0f;
                qkv[(size_t)(row + r) * TRIPLE + col] = f2bf(v);
            }
        }
    }
}

// ---------------------------------------------------------------------------
// k_kv: kv[b,h] (64x64) = sum_n relu(k)[n][m] * v[n][d].  Split-K atomics.
__global__ __launch_bounds__(256) void k_kv(const unsigned short* __restrict__ qkv,
                                            float* __restrict__ kv) // [64][64][64] fp32
{
    __shared__ unsigned short KT[64][136];
    __shared__ unsigned short VT[64][136];
    __shared__ float red[64 * 64];
    int t = threadIdx.x, lane = t & 63, wave = t >> 6;
    int bh = blockIdx.x;
    int b = bh >> 3, h = bh & 7;
    int chunk = blockIdx.y;
    size_t rowbase = (size_t)b * N_ + (size_t)chunk * 1024;
    int kcol = DIM_ + h * 64;
    int vcol = 2 * DIM_ + h * 64;
    int lr = lane & 15;

    f32x4 acc[4][4] = {};
    for (int tile = 0; tile < 8; ++tile) {
        size_t r0 = rowbase + tile * 128;
#pragma unroll
        for (int i = 0; i < 8; ++i) {
            int c = t + 256 * i;
            int r = c >> 4, f4 = (c & 15) * 4;
            us4 kq = *(const us4*)(qkv + (r0 + r) * TRIPLE + kcol + f4);
            us4 vq = *(const us4*)(qkv + (r0 + r) * TRIPLE + vcol + f4);
#pragma unroll
            for (int j = 0; j < 4; ++j) { KT[f4 + j][r] = kq[j]; VT[f4 + j][r] = vq[j]; }
        }
        __syncthreads();
        int kgl = wave * 32 + (lane >> 4) * 8;
        short8 af[4], bfr[4];
#pragma unroll
        for (int i = 0; i < 4; ++i) af[i]  = *(short8*)&KT[i*16 + lr][kgl];
#pragma unroll
        for (int j = 0; j < 4; ++j) bfr[j] = *(short8*)&VT[j*16 + lr][kgl];
#pragma unroll
        for (int i = 0; i < 4; ++i)
#pragma unroll
            for (int j = 0; j < 4; ++j)
                acc[i][j] = __builtin_amdgcn_mfma_f32_16x16x32_bf16(af[i], bfr[j], acc[i][j], 0, 0, 0);
        __syncthreads();
    }
    for (int w = 0; w < 4; ++w) {
        if (wave == w) {
#pragma unroll
            for (int i = 0; i < 4; ++i)
#pragma unroll
                for (int j = 0; j < 4; ++j)
#pragma unroll
                    for (int r = 0; r < 4; ++r) {
                        int m = i*16 + (lane >> 4) * 4 + r;
                        int d = j*16 + lr;
                        if (w == 0) red[m * 64 + d] = acc[i][j][r];
                        else        red[m * 64 + d] += acc[i][j][r];
                    }
        }
        __syncthreads();
    }
    float* kvout = kv + (size_t)bh * 4096;
#pragma unroll
    for (int i = 0; i < 16; ++i) {
        int idx = t + 256 * i;
        atomicAdd(&kvout[idx], red[idx]);
    }
}

// ---------------------------------------------------------------------------
// k_attn2: attn = relu(q) @ kv per head, Q frags loaded direct from global,
// in-place write over Q cols, fp32 LN stats (mu, rsigma) computed from the
// accumulators across all 8 heads and written to smu/srs.
__global__ __launch_bounds__(256) void k_attn2(unsigned short* __restrict__ qkv,
        const float* __restrict__ kv,
        float* __restrict__ smu, float* __restrict__ srs)
{
    __shared__ unsigned short kvT[8][64][72];       // 73.7 KB
    int t = threadIdx.x, lane = t & 63, wave = t >> 6;
    size_t r0 = (size_t)blockIdx.x * 128;
    int b = (int)(r0 >> 13);                        // r0 / 8192
    int lr = lane & 15, kg = (lane >> 4) * 8;
    int wr = wave * 32;

    // stage kv for all 8 heads, transposed to B-layout (kvT[h][d][m']), bf16
    const float* kvb = kv + (size_t)b * 8 * 4096;
#pragma unroll
    for (int i = 0; i < 32; ++i) {
        int idx = (t + 256 * i) * 4;                // 4 consecutive d, same (h,m)
        int h = idx >> 12, m = (idx >> 6) & 63, d0 = idx & 63;
        fl4 v = *(const fl4*)(kvb + idx);
#pragma unroll
        for (int j = 0; j < 4; ++j) kvT[h][d0 + j][m] = f2bf(v[j]);
    }
    __syncthreads();

    float sums[8] = {}, ssums[8] = {};
    for (int h = 0; h < H_; ++h) {
        f32x4 acc[2][4] = {};
#pragma unroll
        for (int ks = 0; ks < 2; ++ks) {
            int colq = h * 64 + ks * 32 + kg;
            short8 af[2], bfr[4];
#pragma unroll
            for (int i = 0; i < 2; ++i)
                af[i] = *(const short8*)(qkv + (r0 + wr + i*16 + lr) * TRIPLE + colq);
            int kgl = ks * 32 + kg;
#pragma unroll
            for (int j = 0; j < 4; ++j) bfr[j] = *(short8*)&kvT[h][j*16 + lr][kgl];
#pragma unroll
            for (int i = 0; i < 2; ++i)
#pragma unroll
                for (int j = 0; j < 4; ++j)
                    acc[i][j] = __builtin_amdgcn_mfma_f32_16x16x32_bf16(af[i], bfr[j], acc[i][j], 0, 0, 0);
        }
#pragma unroll
        for (int i = 0; i < 2; ++i)
#pragma unroll
            for (int j = 0; j < 4; ++j) {
                int row = wr + i*16 + (lane >> 4) * 4;
                int col = h*64 + j*16 + lr;
#pragma unroll
                for (int r = 0; r < 4; ++r) {
                    float v = acc[i][j][r];
                    sums[i*4 + r] += v;
                    ssums[i*4 + r] += v * v;
                    qkv[(r0 + row + r) * TRIPLE + col] = f2bf(v);
                }
            }
    }
    // reduce across the 16 lanes sharing each row group
#pragma unroll
    for (int m = 1; m < 16; m <<= 1) {
#pragma unroll
        for (int i = 0; i < 8; ++i) {
            sums[i]  += __shfl_xor(sums[i],  m);
            ssums[i] += __shfl_xor(ssums[i], m);
        }
    }
    if (lr == 0) {
#pragma unroll
        for (int i = 0; i < 2; ++i)
#pragma unroll
            for (int r = 0; r < 4; ++r) {
                int row = wr + i*16 + (lane >> 4) * 4 + r;
                float mu = sums[i*4 + r] * (1.0f / 512.0f);
                float var = ssums[i*4 + r] * (1.0f / 512.0f) - mu * mu;
                smu[r0 + row] = mu;
                srs[r0 + row] = rsqrtf(fmaxf(var, 0.f) + EPS_);
            }
    }
}

// ---------------------------------------------------------------------------
// k_out2: pure async GEMM  acc = attn @ (lnw*w_out);  epilogue applies
// out = rs*acc - mu*rs*s[col] + tb[col]   (LN folded algebraically).
__global__ __launch_bounds__(256) void k_out2(const unsigned short* __restrict__ qkv,
        const unsigned short* __restrict__ wo2T,    // [512][512] bf16
        const float* __restrict__ smu, const float* __restrict__ srs,
        const float* __restrict__ s, const float* __restrict__ tb,
        float* __restrict__ out)
{
    __shared__ unsigned short As[128 * 32];
    __shared__ unsigned short Bs[128 * 32];
    int t = threadIdx.x, lane = t & 63, wave = t >> 6;
    int m0 = blockIdx.y * 128, n0 = blockIdx.x * 128;
    int wm = (wave & 1) * 64, wn = (wave >> 1) * 64;
    int lr = lane & 15, kg = (lane >> 4) * 8;

    f32x4 acc[4][4] = {};
    for (int k0 = 0; k0 < 512; k0 += 32) {
#pragma unroll
        for (int i = 0; i < 2; ++i) {
            int c = wave * 2 + i;
            int r = c * 16 + (lane >> 2);
            gld16(qkv + (size_t)(m0 + r) * TRIPLE + k0 + (lane & 3) * 8,
                  (char*)As + c * 1024);
            gld16(wo2T + (size_t)(n0 + r) * DIM_ + k0 + (lane & 3) * 8,
                  (char*)Bs + c * 1024);
        }
        __syncthreads();
        short8 af[4], bfr[4];
#pragma unroll
        for (int i = 0; i < 4; ++i) af[i]  = *(short8*)&As[(wm + i*16 + lr) * 32 + kg];
#pragma unroll
        for (int j = 0; j < 4; ++j) bfr[j] = *(short8*)&Bs[(wn + j*16 + lr) * 32 + kg];
#pragma unroll
        for (int i = 0; i < 4; ++i)
#pragma unroll
            for (int j = 0; j < 4; ++j)
                acc[i][j] = __builtin_amdgcn_mfma_f32_16x16x32_bf16(af[i], bfr[j], acc[i][j], 0, 0, 0);
        __syncthreads();
    }
#pragma unroll
    for (int i = 0; i < 4; ++i) {
        int row = m0 + wm + i*16 + (lane >> 4) * 4;
        float mu4[4], rs4[4];
#pragma unroll
        for (int r = 0; r < 4; ++r) { mu4[r] = smu[row + r]; rs4[r] = srs[row + r]; }
#pragma unroll
        for (int j = 0; j < 4; ++j) {
            int col = n0 + wn + j*16 + lr;
            float sn = s[col], tbn = tb[col];
#pragma unroll
            for (int r = 0; r < 4; ++r)
                out[(size_t)(row + r) * DIM_ + col] = rs4[r] * acc[i][j][r] - mu4[r] * rs4[r] * sn + tbn;
        }
    }
}

// ---------------------------------------------------------------------------
extern "C" void kernel_launch(void* const* d_in, const int* in_sizes, int n_in,
                              void* d_out, int out_size, void* d_ws, size_t ws_size,
                              hipStream_t stream) {
    (void)in_sizes; (void)n_in; (void)out_size; (void)ws_size;
    const float* x     = (const float*)d_in[0];
    const float* w_qkv = (const float*)d_in[1];
    const float* ln_w  = (const float*)d_in[2];
    const float* ln_b  = (const float*)d_in[3];
    const float* w_out = (const float*)d_in[4];
    const float* b_out = (const float*)d_in[5];
    float* out = (float*)d_out;

    char* ws = (char*)d_ws;
    const size_t QKV_BYTES = (size_t)ROWS * TRIPLE * sizeof(unsigned short); // 201326592
    const size_t KV_BYTES  = (size_t)64 * 64 * 64 * sizeof(float);           // 1048576
    const size_t WQT_BYTES = (size_t)TRIPLE * DIM_ * sizeof(unsigned short); // 1572864
    const size_t WO2_BYTES = (size_t)DIM_ * DIM_ * sizeof(unsigned short);   // 524288
    const size_t MU_BYTES  = (size_t)ROWS * sizeof(float);                   // 262144
    unsigned short* qkv   = (unsigned short*)ws;                 ws += QKV_BYTES;
    float*          kvbuf = (float*)ws;                          ws += KV_BYTES;
    unsigned short* wqkvT = (unsigned short*)ws;                 ws += WQT_BYTES;
    unsigned short* wo2T  = (unsigned short*)ws;                 ws += WO2_BYTES;
    float*          smu   = (float*)ws;                          ws += MU_BYTES;
    float*          srs   = (float*)ws;                          ws += MU_BYTES;
    float*          sbuf  = (float*)ws;                          ws += 2048;
    float*          tbbuf = (float*)ws;

    hipMemsetAsync(kvbuf, 0, KV_BYTES, stream);
    k_prep<<<3072, 256, 0, stream>>>(w_qkv, w_out, ln_w, wqkvT, wo2T);
    k_sums<<<2, 256, 0, stream>>>(w_out, ln_w, ln_b, b_out, sbuf, tbbuf);
    k_qkv_b<<<dim3(12, 512), 256, 0, stream>>>(x, wqkvT, qkv);
    k_kv<<<dim3(64, 8), 256, 0, stream>>>(qkv, kvbuf);
    k_attn2<<<512, 256, 0, stream>>>(qkv, kvbuf, smu, srs);
    k_out2<<<dim3(4, 512), 256, 0, stream>>>(qkv, wo2T, smu, srs, sbuf, tbbuf, out);
}